// Round 3
// baseline (524.462 us; speedup 1.0000x reference)
//
#include <hip/hip_runtime.h>
#include <hip/hip_cooperative_groups.h>

namespace cg = cooperative_groups;

#define N_S   65536
#define DXF   1024
#define DD    256
#define NM1   65535.0f
#define EPSR  0.001f

typedef __attribute__((ext_vector_type(4)))  float          f32x4;
typedef __attribute__((ext_vector_type(16))) float          f32x16;
typedef __attribute__((ext_vector_type(8)))  short          bf16x8;
typedef __attribute__((ext_vector_type(4)))  unsigned short ushort4_t;
typedef __attribute__((ext_vector_type(8)))  unsigned short ushort8_t;

__device__ __forceinline__ unsigned short f2bf(float f){
  unsigned u = __float_as_uint(f);
  u += 0x7fffu + ((u >> 16) & 1u);   // RNE
  return (unsigned short)(u >> 16);
}
__device__ __forceinline__ float bf2f(unsigned short h){
  return __uint_as_float(((unsigned)h) << 16);
}
__device__ __forceinline__ f32x4 mfma16(bf16x8 a, bf16x8 b, f32x4 c){
  return __builtin_amdgcn_mfma_f32_16x16x32_bf16(a, b, c, 0, 0, 0);
}
__device__ __forceinline__ f32x16 mfma32(bf16x8 a, bf16x8 b, f32x16 c){
  return __builtin_amdgcn_mfma_f32_32x32x16_bf16(a, b, c, 0, 0, 0);
}
__device__ __forceinline__ void gld_lds16(const unsigned short* g, unsigned short* l){
  __builtin_amdgcn_global_load_lds(
      (const __attribute__((address_space(1))) unsigned int*)(const void*)g,
      (__attribute__((address_space(3))) unsigned int*)(void*)l, 16, 0, 0);
}
__device__ __forceinline__ bf16x8 pack8(float4 a, float4 b){
  union { unsigned u[4]; bf16x8 v; } r;
  asm("v_cvt_pk_bf16_f32 %0, %1, %2" : "=v"(r.u[0]) : "v"(a.x), "v"(a.y));
  asm("v_cvt_pk_bf16_f32 %0, %1, %2" : "=v"(r.u[1]) : "v"(a.z), "v"(a.w));
  asm("v_cvt_pk_bf16_f32 %0, %1, %2" : "=v"(r.u[2]) : "v"(b.x), "v"(b.y));
  asm("v_cvt_pk_bf16_f32 %0, %1, %2" : "=v"(r.u[3]) : "v"(b.z), "v"(b.w));
  return r.v;
}

// ---------------- scalars: STG regularizers + zero accumulators ------------
__global__ void k_scalars(const float* __restrict__ mux, const float* __restrict__ muy,
                          float* __restrict__ sx, float* __restrict__ sy,
                          float* __restrict__ scal){
  __shared__ float red[512];
  int v = blockIdx.x;
  const float* mu = v ? muy : mux;
  int t = threadIdx.x;
  float a = 0.5f * (1.f + erff(mu[t]       * 1.41421356237f));
  float b = 0.5f * (1.f + erff(mu[t + 512] * 1.41421356237f));
  red[t] = a + b;
  __syncthreads();
  for (int s = 256; s > 0; s >>= 1){
    if (t < s) red[t] += red[t + s];
    __syncthreads();
  }
  if (t == 0) scal[2 + v] = 0.1f * red[0] / 1024.f;
  if (v == 0 && t < 3) scal[4 + t] = 0.f;   // trace acc + two uint norm slots
  if (t < 256) (v ? sy : sx)[t] = 0.f;
}

// ---------------- build W'^T = (diag(gate)*W)^T in bf16, [256][1024] -------
__global__ void k_prep(const float* __restrict__ Wx, const float* __restrict__ Wy,
                       const float* __restrict__ mux, const float* __restrict__ muy,
                       unsigned short* __restrict__ WTx, unsigned short* __restrict__ WTy){
  int v = blockIdx.y;
  const float* W  = v ? Wy  : Wx;
  const float* mu = v ? muy : mux;
  unsigned short* WT = v ? WTy : WTx;
  int j = threadIdx.x;
  #pragma unroll
  for (int r = 0; r < 4; ++r){
    int k = blockIdx.x * 4 + r;
    float g = fminf(fmaxf(mu[k] + 0.5f, 0.f), 1.f);
    WT[(size_t)j * DXF + k] = f2bf(g * W[(size_t)k * DD + j]);
  }
}

// ---------------- big GEMM: Xh = X @ W'  (65536x1024 @ 1024x256) -> bf16 ---
// block: 256 thr (4 waves), 128 rows; wave tile 32x256; 32x32x16 MFMA
// A: global->reg->cvt_pk, 1-step prefetch. B: global_load_lds dbuf.
// Counted vmcnt(4) + raw s_barrier keeps A prefetch in flight across barrier.
__global__ __launch_bounds__(256, 2) void k_gemm3(
    const float* __restrict__ X, const float* __restrict__ Y,
    const unsigned short* __restrict__ WTx, const unsigned short* __restrict__ WTy,
    unsigned short* __restrict__ Xhb, unsigned short* __restrict__ Yhb){
  const float* A = blockIdx.z ? Y : X;
  const unsigned short* WT = blockIdx.z ? WTy : WTx;
  unsigned short* Out = blockIdx.z ? Yhb : Xhb;

  __shared__ unsigned short lds[16384];    // 2 x 8192 shorts (32KB)

  int tid = threadIdx.x, lane = tid & 63, wid = tid >> 6;
  int row0 = blockIdx.x * 128;
  int arow = row0 + wid * 32 + (lane & 31);
  const float* ap = A + (size_t)arow * DXF + ((lane >> 5) << 3);

  f32x16 acc[8] = {};
  float4 ar0, ar1, ar2, ar3, an0, an1, an2, an3;

  auto stage = [&](int buf, int k0){
    #pragma unroll
    for (int r = 0; r < 4; ++r){
      const unsigned short* s = WT + (size_t)tid * DXF + k0 + (r >> 1) * 16 + (r & 1) * 8;
      unsigned short* l = lds + buf * 8192 + r * 2048 + tid * 8;
      gld_lds16(s, l);
    }
  };

  stage(0, 0);
  asm volatile("" ::: "memory");           // pin order: stage before A loads
  ar0 = *(const float4*)(ap + 0);
  ar1 = *(const float4*)(ap + 4);
  ar2 = *(const float4*)(ap + 16);
  ar3 = *(const float4*)(ap + 20);

  for (int ks = 0; ks < 32; ++ks){
    // oldest 4 outstanding vmem = this step's B stage; A prefetch stays in flight
    asm volatile("s_waitcnt vmcnt(4)" ::: "memory");
    __builtin_amdgcn_s_barrier();
    if (ks + 1 < 32){
      int kn = ks * 32 + 32;
      stage((ks + 1) & 1, kn);
      asm volatile("" ::: "memory");       // pin order: stage before A loads
      an0 = *(const float4*)(ap + kn);
      an1 = *(const float4*)(ap + kn + 4);
      an2 = *(const float4*)(ap + kn + 16);
      an3 = *(const float4*)(ap + kn + 20);
    }
    bf16x8 af0 = pack8(ar0, ar1);
    bf16x8 af1 = pack8(ar2, ar3);
    const unsigned short* bb = lds + (ks & 1) * 8192 + ((lane >> 5) << 11) + ((lane & 31) << 3);
    #pragma unroll
    for (int ni = 0; ni < 8; ++ni)
      acc[ni] = mfma32(af0, *(const bf16x8*)(bb + ni * 256), acc[ni]);
    #pragma unroll
    for (int ni = 0; ni < 8; ++ni)
      acc[ni] = mfma32(af1, *(const bf16x8*)(bb + 4096 + ni * 256), acc[ni]);
    ar0 = an0; ar1 = an1; ar2 = an2; ar3 = an3;
  }

  // epilogue: 2-pass LDS transpose (32KB) -> coalesced bf16 stores
  __syncthreads();
  #pragma unroll
  for (int p = 0; p < 2; ++p){
    if ((wid >> 1) == p){
      unsigned short* wl = lds + (wid & 1) * 8192;   // 32 rows x 256 cols
      #pragma unroll
      for (int ni = 0; ni < 8; ++ni){
        int col = ni * 32 + (lane & 31);
        #pragma unroll
        for (int reg = 0; reg < 16; ++reg){
          int row = (reg & 3) + 8 * (reg >> 2) + 4 * (lane >> 5);
          wl[row * 256 + col] = f2bf(acc[ni][reg]);
        }
      }
    }
    __syncthreads();
    unsigned short* ob = Out + (size_t)(row0 + p * 64) * DD;
    #pragma unroll
    for (int r = 0; r < 8; ++r){
      int off = r * 2048 + tid * 8;
      *(ushort8_t*)(ob + off) = *(const ushort8_t*)(lds + off);
    }
    if (p == 0) __syncthreads();
  }
}

// ---------------- Gram kernel: split-K partials of Xh^T Xh / Yh^T Yh / Yh^T Xh
__global__ __launch_bounds__(512) void k_gram(
    const unsigned short* __restrict__ Xhb, const unsigned short* __restrict__ Yhb,
    float* __restrict__ part, float* __restrict__ sx, float* __restrict__ sy, int P){
  int type = blockIdx.z;                   // 0:xx 1:yy 2:yx
  int p = blockIdx.x;
  int chunk = N_S / P;
  int r0 = p * chunk;
  const unsigned short* Asrc = (type == 0) ? Xhb : Yhb;
  const unsigned short* Bsrc = (type == 1) ? Yhb : Xhb;
  bool dualB = (type == 2);

  __shared__ unsigned short At[256][40];
  __shared__ unsigned short Bt[256][40];

  int tid = threadIdx.x;
  int lane = tid & 63, wid = tid >> 6;
  int wr = wid >> 1, wc = wid & 1;

  f32x4 acc[4][8] = {};
  float cs0 = 0.f, cs1 = 0.f;

  int cp  = tid & 127;
  int kb0 = tid >> 7;

  unsigned ua[2][4], ub[2][4];

  auto loadT = [&](int ks){
    int base = r0 + ks * 32;
    #pragma unroll
    for (int r = 0; r < 2; ++r){
      int kb = kb0 + r * 4;
      #pragma unroll
      for (int kr = 0; kr < 4; ++kr){
        ua[r][kr] = *(const unsigned*)(Asrc + (size_t)(base + kb * 4 + kr) * DD + cp * 2);
        if (dualB)
          ub[r][kr] = *(const unsigned*)(Bsrc + (size_t)(base + kb * 4 + kr) * DD + cp * 2);
      }
    }
  };
  auto storeT = [&](){
    #pragma unroll
    for (int r = 0; r < 2; ++r){
      int kb = kb0 + r * 4;
      ushort4_t lo = { (unsigned short)ua[r][0], (unsigned short)ua[r][1],
                       (unsigned short)ua[r][2], (unsigned short)ua[r][3] };
      ushort4_t hi = { (unsigned short)(ua[r][0] >> 16), (unsigned short)(ua[r][1] >> 16),
                       (unsigned short)(ua[r][2] >> 16), (unsigned short)(ua[r][3] >> 16) };
      *(ushort4_t*)&At[cp * 2][kb * 4]     = lo;
      *(ushort4_t*)&At[cp * 2 + 1][kb * 4] = hi;
      if (type < 2){
        #pragma unroll
        for (int kr = 0; kr < 4; ++kr){
          cs0 += bf2f((unsigned short)ua[r][kr]);
          cs1 += bf2f((unsigned short)(ua[r][kr] >> 16));
        }
      }
      if (dualB){
        ushort4_t lob = { (unsigned short)ub[r][0], (unsigned short)ub[r][1],
                          (unsigned short)ub[r][2], (unsigned short)ub[r][3] };
        ushort4_t hib = { (unsigned short)(ub[r][0] >> 16), (unsigned short)(ub[r][1] >> 16),
                          (unsigned short)(ub[r][2] >> 16), (unsigned short)(ub[r][3] >> 16) };
        *(ushort4_t*)&Bt[cp * 2][kb * 4]     = lob;
        *(ushort4_t*)&Bt[cp * 2 + 1][kb * 4] = hib;
      }
    }
  };

  unsigned short (*Btp)[40] = dualB ? Bt : At;

  int KS = chunk / 32;
  loadT(0);
  for (int ks = 0; ks < KS; ++ks){
    __syncthreads();
    storeT();
    __syncthreads();
    if (ks + 1 < KS) loadT(ks + 1);
    bf16x8 af[4], bfv[8];
    #pragma unroll
    for (int mi = 0; mi < 4; ++mi)
      af[mi] = *(const bf16x8*)&At[wr * 64 + mi * 16 + (lane & 15)][(lane >> 4) * 8];
    #pragma unroll
    for (int ni = 0; ni < 8; ++ni)
      bfv[ni] = *(const bf16x8*)&Btp[wc * 128 + ni * 16 + (lane & 15)][(lane >> 4) * 8];
    #pragma unroll
    for (int mi = 0; mi < 4; ++mi)
      #pragma unroll
      for (int ni = 0; ni < 8; ++ni)
        acc[mi][ni] = mfma16(af[mi], bfv[ni], acc[mi][ni]);
  }

  float* dst = part + ((size_t)p * 3 + type) * 65536;
  #pragma unroll
  for (int mi = 0; mi < 4; ++mi)
    #pragma unroll
    for (int ni = 0; ni < 8; ++ni)
      #pragma unroll
      for (int rr = 0; rr < 4; ++rr){
        int grow = wr * 64 + mi * 16 + (lane >> 4) * 4 + rr;
        int gcol = wc * 128 + ni * 16 + (lane & 15);
        dst[(size_t)grow * 256 + gcol] = acc[mi][ni][rr];
      }

  if (type < 2){
    __syncthreads();
    float* red = (float*)&At[0][0];
    red[kb0 * 256 + cp * 2]     = cs0;
    red[kb0 * 256 + cp * 2 + 1] = cs1;
    __syncthreads();
    if (tid < 256){
      float s = red[tid] + red[256 + tid] + red[512 + tid] + red[768 + tid];
      atomicAdd((type == 0 ? sx : sy) + tid, s);
    }
  }
}

// ---------------- reduce partials -> A, B (fp32 + bf16), Cyx bf16 (+T) -----
__global__ void k_reduce(const float* __restrict__ part, const float* __restrict__ sx,
                         const float* __restrict__ sy, float* __restrict__ Am,
                         float* __restrict__ Bm,
                         unsigned short* __restrict__ Abf, unsigned short* __restrict__ Bbf,
                         unsigned short* __restrict__ Cbf, unsigned short* __restrict__ CbfT,
                         int P){
  int i = blockIdx.x, j = threadIdx.x;
  size_t idx = (size_t)i * 256 + j;
  float gxx = 0.f, gyy = 0.f, gyx = 0.f;
  for (int p = 0; p < P; ++p){
    const float* b = part + (size_t)p * 3 * 65536;
    gxx += b[idx];
    gyy += b[65536 + idx];
    gyx += b[131072 + idx];
  }
  float invn1 = 1.f / NM1;
  float invn  = 1.f / (float)N_S;
  float sxi = sx[i], sxj = sx[j], syi = sy[i], syj = sy[j];
  float diag = (i == j) ? 1.f : 0.f;
  float am = (gyy - syi * syj * invn) * invn1 + diag * (2.f * EPSR);
  float bm = (gxx - sxi * sxj * invn) * invn1 + diag * EPSR;
  float cv = (gyx - syi * sxj * invn) * invn1;
  Am[idx] = am;  Bm[idx] = bm;
  Abf[idx] = f2bf(am);
  Bbf[idx] = f2bf(bm);
  Cbf[idx] = f2bf(cv);
  CbfT[(size_t)j * 256 + i] = f2bf(cv);
}

// ---------------- cooperative tail: norms, init, 8x NS, U/V, trace ---------
__device__ __forceinline__ f32x4 ns_tile(const unsigned short* __restrict__ Ar,
                                         const unsigned short* __restrict__ Br,
                                         int rt, int ct, int lane){
  const unsigned short* ap = Ar + (size_t)(rt * 16 + (lane & 15)) * 256 + ((lane >> 4) << 3);
  const unsigned short* bp = Br + (size_t)(ct * 16 + (lane & 15)) * 256 + ((lane >> 4) << 3);
  f32x4 acc = {};
  #pragma unroll
  for (int kb = 0; kb < 8; ++kb){
    bf16x8 a = *(const bf16x8*)(ap + kb * 32);
    bf16x8 b = *(const bf16x8*)(bp + kb * 32);
    acc = mfma16(a, b, acc);
  }
  return acc;
}

__global__ __launch_bounds__(512) void k_ns(
    const float* __restrict__ Am, const float* __restrict__ Bm,
    const unsigned short* __restrict__ Abf, const unsigned short* __restrict__ Bbf,
    const unsigned short* __restrict__ Cbf, const unsigned short* __restrict__ CbfT,
    unsigned short* __restrict__ X0, unsigned short* __restrict__ X1,
    unsigned short* __restrict__ Tb, float* __restrict__ U, float* __restrict__ V,
    float* __restrict__ scal, float* __restrict__ out){
  cg::grid_group grid = cg::this_grid();
  __shared__ float red[512];
  int bid = blockIdx.x, tid = threadIdx.x;
  int lane = tid & 63;
  unsigned* su = (unsigned*)scal;

  // phase 0: inf-norms of A (blocks 0-15) and B (blocks 16-31)
  {
    int mat = bid >> 4;
    int row = (bid & 15) * 16 + (tid >> 5);
    const float* M = mat ? Bm : Am;
    float s = 0.f;
    for (int j = tid & 31; j < 256; j += 32) s += fabsf(M[(size_t)row * 256 + j]);
    #pragma unroll
    for (int o = 16; o > 0; o >>= 1) s += __shfl_xor(s, o);
    if ((lane & 31) == 0) atomicMax(su + 5 + mat, __float_as_uint(s));
  }
  grid.sync();

  // phase 1: X0 = alpha * I (bf16), both matrices
  float aa = 1.f / __uint_as_float(su[5]);
  float ab = 1.f / __uint_as_float(su[6]);
  #pragma unroll
  for (int r = 0; r < 8; ++r){
    int idx = (bid * 512 + tid) + r * 16384;
    int mat = idx >> 16, e = idx & 65535;
    X0[idx] = ((e >> 8) == (e & 255)) ? f2bf(mat ? ab : aa) : (unsigned short)0;
  }
  grid.sync();

  int wave = bid * 8 + (tid >> 6);          // 0..255 ; 512 tiles total
  unsigned short *Xc = X0, *Xn = X1;

  for (int it = 0; it < 8; ++it){
    // half 1: T = M @ X
    #pragma unroll
    for (int s = 0; s < 2; ++s){
      int t = wave * 2 + s;
      int mat = t >> 8, rt = (t >> 4) & 15, ct = t & 15;
      const unsigned short* M = mat ? Bbf : Abf;
      f32x4 acc = ns_tile(M, Xc + mat * 65536, rt, ct, lane);
      int col = ct * 16 + (lane & 15);
      #pragma unroll
      for (int rr = 0; rr < 4; ++rr){
        int row = rt * 16 + (lane >> 4) * 4 + rr;
        Tb[mat * 65536 + row * 256 + col] = f2bf(acc[rr]);
      }
    }
    grid.sync();
    // half 2: X' = 2X - X @ T
    #pragma unroll
    for (int s = 0; s < 2; ++s){
      int t = wave * 2 + s;
      int mat = t >> 8, rt = (t >> 4) & 15, ct = t & 15;
      f32x4 acc = ns_tile(Xc + mat * 65536, Tb + mat * 65536, rt, ct, lane);
      int col = ct * 16 + (lane & 15);
      #pragma unroll
      for (int rr = 0; rr < 4; ++rr){
        int row = rt * 16 + (lane >> 4) * 4 + rr;
        size_t o = (size_t)mat * 65536 + row * 256 + col;
        Xn[o] = f2bf(2.f * bf2f(Xc[o]) - acc[rr]);
      }
    }
    grid.sync();
    unsigned short* tmp = Xc; Xc = Xn; Xn = tmp;
  }

  // U = XA @ Cyx (B-op = CbfT), V = XB @ Cyx^T (B-op = Cbf); fp32 out
  #pragma unroll
  for (int s = 0; s < 2; ++s){
    int t = wave * 2 + s;
    int mat = t >> 8, rt = (t >> 4) & 15, ct = t & 15;
    f32x4 acc = ns_tile(Xc + mat * 65536, mat ? Cbf : CbfT, rt, ct, lane);
    float* D = mat ? V : U;
    int col = ct * 16 + (lane & 15);
    #pragma unroll
    for (int rr = 0; rr < 4; ++rr){
      int row = rt * 16 + (lane >> 4) * 4 + rr;
      D[row * 256 + col] = acc[rr];
    }
  }
  grid.sync();

  // trace(U @ V)
  float tr = 0.f;
  #pragma unroll
  for (int r = 0; r < 4; ++r){
    int idx = bid * 2048 + r * 512 + tid;
    int i = idx >> 8, j = idx & 255;
    tr += U[idx] * V[j * 256 + i];
  }
  red[tid] = tr;
  __syncthreads();
  for (int s = 256; s > 0; s >>= 1){
    if (tid < s) red[tid] += red[tid + s];
    __syncthreads();
  }
  if (tid == 0) atomicAdd(scal + 4, red[0]);
  grid.sync();
  if (bid == 0 && tid == 0)
    out[0] = -scal[4] / 256.f + scal[2] + scal[3];
}

extern "C" void kernel_launch(void* const* d_in, const int* in_sizes, int n_in,
                              void* d_out, int out_size, void* d_ws, size_t ws_size,
                              hipStream_t stream){
  (void)in_sizes; (void)n_in; (void)out_size;
  const float* X   = (const float*)d_in[0];
  const float* Y   = (const float*)d_in[1];
  const float* mux = (const float*)d_in[2];
  const float* muy = (const float*)d_in[3];
  const float* Wx  = (const float*)d_in[4];
  const float* Wy  = (const float*)d_in[6];
  float* out = (float*)d_out;
  char* ws = (char*)d_ws;

  const size_t MB = 1ull << 20;
  const size_t KB = 1024;
  size_t oXHB = 0;
  size_t oYHB = 32 * MB;
  size_t oWTX = 64 * MB;
  size_t oWTY = oWTX + 512 * KB;
  size_t oSX  = oWTY + 512 * KB;
  size_t oSY  = oSX + 4 * KB;
  size_t oSC  = oSY + 4 * KB;
  size_t oA   = oSC + 4 * KB;
  size_t oB   = oA   + 256 * KB;
  size_t oABF = oB   + 256 * KB;
  size_t oBBF = oABF + 128 * KB;
  size_t oCBF = oBBF + 128 * KB;
  size_t oCBT = oCBF + 128 * KB;
  size_t oX0  = oCBT + 128 * KB;
  size_t oX1  = oX0  + 256 * KB;
  size_t oTB  = oX1  + 256 * KB;
  size_t oU   = oTB  + 256 * KB;
  size_t oV   = oU   + 256 * KB;
  size_t oPart = 68 * MB;

  size_t per = 3ull * 65536 * 4;
  int P = 128;
  while (P > 8 && oPart + (size_t)P * per > ws_size) P >>= 1;

  unsigned short* Xhb = (unsigned short*)(ws + oXHB);
  unsigned short* Yhb = (unsigned short*)(ws + oYHB);
  unsigned short* WTx = (unsigned short*)(ws + oWTX);
  unsigned short* WTy = (unsigned short*)(ws + oWTY);
  float* sx   = (float*)(ws + oSX);
  float* sy   = (float*)(ws + oSY);
  float* scal = (float*)(ws + oSC);
  float* Am   = (float*)(ws + oA);
  float* Bm   = (float*)(ws + oB);
  unsigned short* Abf  = (unsigned short*)(ws + oABF);
  unsigned short* Bbf  = (unsigned short*)(ws + oBBF);
  unsigned short* Cbf  = (unsigned short*)(ws + oCBF);
  unsigned short* CbfT = (unsigned short*)(ws + oCBT);
  unsigned short* X0   = (unsigned short*)(ws + oX0);
  unsigned short* X1   = (unsigned short*)(ws + oX1);
  unsigned short* Tb   = (unsigned short*)(ws + oTB);
  float* U    = (float*)(ws + oU);
  float* V    = (float*)(ws + oV);
  float* part = (float*)(ws + oPart);

  k_scalars<<<2, 512, 0, stream>>>(mux, muy, sx, sy, scal);
  k_prep<<<dim3(256, 2), 256, 0, stream>>>(Wx, Wy, mux, muy, WTx, WTy);
  k_gemm3<<<dim3(512, 1, 2), 256, 0, stream>>>(X, Y, WTx, WTy, Xhb, Yhb);
  k_gram<<<dim3(P, 1, 3), 512, 0, stream>>>(Xhb, Yhb, part, sx, sy, P);
  k_reduce<<<256, 256, 0, stream>>>(part, sx, sy, Am, Bm, Abf, Bbf, Cbf, CbfT, P);

  void* args[] = { (void*)&Am, (void*)&Bm, (void*)&Abf, (void*)&Bbf,
                   (void*)&Cbf, (void*)&CbfT, (void*)&X0, (void*)&X1,
                   (void*)&Tb, (void*)&U, (void*)&V, (void*)&scal, (void*)&out };
  hipLaunchCooperativeKernel((const void*)k_ns, dim3(32), dim3(512), args, 0, stream);
}